// Round 1
// baseline (285.886 us; speedup 1.0000x reference)
//
#include <hip/hip_runtime.h>
#include <hip/hip_bf16.h>
#include <math.h>
#include <stdint.h>

// MHA pipeline: split_x + transpose weights (hi/lo bf16) + rope tables ->
// split QKV GEMM (3-term bf16 MFMA = fp32-ish precision) -> rope+scatter ->
// flash attention (bf16 MFMA) -> out GEMM (bf16 MFMA, fp32 out).

typedef __bf16 bf16;
typedef __bf16 bf16x8 __attribute__((ext_vector_type(8)));
typedef __bf16 bf16x4 __attribute__((ext_vector_type(4)));
typedef float f32x4 __attribute__((ext_vector_type(4)));

#define AS1 __attribute__((address_space(1)))
#define AS3 __attribute__((address_space(3)))

__device__ __forceinline__ void gload_lds16(const void* g, void* l) {
  __builtin_amdgcn_global_load_lds((const AS1 void*)g, (AS3 void*)l, 16, 0, 0);
}

__device__ __forceinline__ f32x4 mfma16(bf16x8 a, bf16x8 b, f32x4 c) {
  return __builtin_amdgcn_mfma_f32_16x16x32_bf16(a, b, c, 0, 0, 0);
}

#define S_LEN 2048

// ---------------- prep kernels ----------------

__global__ void k_split_x(const float* __restrict__ x, bf16* __restrict__ xh,
                          bf16* __restrict__ xl) {
  int i = blockIdx.x * 256 + threadIdx.x;   // grid covers n/4 exactly
  float4 v = ((const float4*)x)[i];
  float vv[4] = {v.x, v.y, v.z, v.w};
  bf16x4 h, l;
#pragma unroll
  for (int j = 0; j < 4; j++) {
    bf16 hb = (bf16)vv[j];
    h[j] = hb;
    l[j] = (bf16)(vv[j] - (float)hb);
  }
  ((bf16x4*)xh)[i] = h;
  ((bf16x4*)xl)[i] = l;
}

// w_qkv (1024,3072) fp32 -> W^T hi/lo bf16 (3072,1024)
__global__ void k_wt_qkv(const float* __restrict__ w, bf16* __restrict__ bth,
                         bf16* __restrict__ btl) {
  __shared__ float t[32][33];
  int n0 = blockIdx.x * 32, k0 = blockIdx.y * 32;
  int tx = threadIdx.x & 31, ty = threadIdx.x >> 5;
#pragma unroll
  for (int i = 0; i < 4; i++)
    t[ty + 8 * i][tx] = w[(size_t)(k0 + ty + 8 * i) * 3072 + n0 + tx];
  __syncthreads();
#pragma unroll
  for (int i = 0; i < 4; i++) {
    int r = ty + 8 * i;
    float v = t[tx][r];                      // = w[k0+tx][n0+r]
    size_t o = (size_t)(n0 + r) * 1024 + k0 + tx;
    bf16 hb = (bf16)v;
    bth[o] = hb;
    btl[o] = (bf16)(v - (float)hb);
  }
}

// w_out (1024,1024) fp32 -> W^T bf16 (1024,1024)
__global__ void k_wt_out(const float* __restrict__ w, bf16* __restrict__ bt) {
  __shared__ float t[32][33];
  int n0 = blockIdx.x * 32, k0 = blockIdx.y * 32;
  int tx = threadIdx.x & 31, ty = threadIdx.x >> 5;
#pragma unroll
  for (int i = 0; i < 4; i++)
    t[ty + 8 * i][tx] = w[(size_t)(k0 + ty + 8 * i) * 1024 + n0 + tx];
  __syncthreads();
#pragma unroll
  for (int i = 0; i < 4; i++) {
    int r = ty + 8 * i;
    bt[(size_t)(n0 + r) * 1024 + k0 + tx] = (bf16)t[tx][r];
  }
}

// cos/sin tables (2048, 32) fp32
__global__ void k_rope_tables(float* __restrict__ ct, float* __restrict__ st) {
  int i = blockIdx.x * 256 + threadIdx.x;   // 65536
  int s = i >> 5, j = i & 31;
  double invf = pow(10000.0, -(double)j / 32.0);
  double a = (double)s * invf;
  ct[i] = (float)cos(a);
  st[i] = (float)sin(a);
}

// ---------------- QKV GEMM: C(4096,3072) = [Xh+Xl](4096,1024) @ [Wh+Wl]^T ----------------
// 128x128 tile, BK=32, 4 waves (2x2), split-precision: 3 MFMA per frag pair.
__global__ __launch_bounds__(256, 2) void k_gemm_qkv(
    const bf16* __restrict__ Ah, const bf16* __restrict__ Al,
    const bf16* __restrict__ Bh, const bf16* __restrict__ Bl,
    bf16* __restrict__ C) {
  const int K = 1024, N = 3072;
  __shared__ __align__(16) bf16 sAh[128 * 32];
  __shared__ __align__(16) bf16 sAl[128 * 32];
  __shared__ __align__(16) bf16 sBh[128 * 32];
  __shared__ __align__(16) bf16 sBl[128 * 32];
  int tid = threadIdx.x, lane = tid & 63, wid = tid >> 6;
  int m0 = blockIdx.x * 128, n0 = blockIdx.y * 128;
  int wm = wid >> 1, wn = wid & 1;

  f32x4 acc[4][4];
#pragma unroll
  for (int a = 0; a < 4; a++)
#pragma unroll
    for (int b = 0; b < 4; b++) acc[a][b] = (f32x4){0.f, 0.f, 0.f, 0.f};

  for (int k0 = 0; k0 < K; k0 += 32) {
    // stage 4 tiles (each 128x32 bf16 = 8KB). Swizzle: col16 ^= (row>>1)&3,
    // applied on the GLOBAL source (dest stays linear for global_load_lds).
#pragma unroll
    for (int p = 0; p < 2; p++) {
      int slot = p * 256 + tid;
      int row = slot >> 2, c16 = slot & 3;
      int cs = c16 ^ ((row >> 1) & 3);
      char* lb = (char*)nullptr;
      int ldsoff = (p * 256 + wid * 64) * 16;
      size_t ga = (size_t)(m0 + row) * K + k0 + cs * 8;
      size_t gb = (size_t)(n0 + row) * K + k0 + cs * 8;
      (void)lb;
      gload_lds16(Ah + ga, (char*)sAh + ldsoff);
      gload_lds16(Al + ga, (char*)sAl + ldsoff);
      gload_lds16(Bh + gb, (char*)sBh + ldsoff);
      gload_lds16(Bl + gb, (char*)sBl + ldsoff);
    }
    __syncthreads();

    bf16x8 fah[4], fal[4], fbh[4], fbl[4];
#pragma unroll
    for (int mf = 0; mf < 4; mf++) {
      int row = wm * 64 + mf * 16 + (lane & 15);
      int c16 = (lane >> 4) ^ ((row >> 1) & 3);
      int off = row * 64 + c16 * 16;
      fah[mf] = *(const bf16x8*)((const char*)sAh + off);
      fal[mf] = *(const bf16x8*)((const char*)sAl + off);
    }
#pragma unroll
    for (int nf = 0; nf < 4; nf++) {
      int row = wn * 64 + nf * 16 + (lane & 15);
      int c16 = (lane >> 4) ^ ((row >> 1) & 3);
      int off = row * 64 + c16 * 16;
      fbh[nf] = *(const bf16x8*)((const char*)sBh + off);
      fbl[nf] = *(const bf16x8*)((const char*)sBl + off);
    }
#pragma unroll
    for (int mf = 0; mf < 4; mf++)
#pragma unroll
      for (int nf = 0; nf < 4; nf++) {
        acc[mf][nf] = mfma16(fah[mf], fbh[nf], acc[mf][nf]);
        acc[mf][nf] = mfma16(fah[mf], fbl[nf], acc[mf][nf]);
        acc[mf][nf] = mfma16(fal[mf], fbh[nf], acc[mf][nf]);
      }
    __syncthreads();
  }

#pragma unroll
  for (int mf = 0; mf < 4; mf++)
#pragma unroll
    for (int nf = 0; nf < 4; nf++)
#pragma unroll
      for (int r = 0; r < 4; r++) {
        int row = m0 + wm * 64 + mf * 16 + (lane >> 4) * 4 + r;
        int col = n0 + wn * 64 + nf * 16 + (lane & 15);
        C[(size_t)row * N + col] = (bf16)acc[mf][nf][r];
      }
}

// ---------------- RoPE + scatter ----------------
// QKV (4096,3072): col n -> head n/192, which (n/64)%3, d n%64.
// Outputs: Q,K per-head [bh][s][d]; V transposed [bh][d][s].
__global__ void k_rope_scatter(const bf16* __restrict__ QKV,
                               const float* __restrict__ ct,
                               const float* __restrict__ st,
                               bf16* __restrict__ Q, bf16* __restrict__ Kb,
                               bf16* __restrict__ Vt) {
  __shared__ __align__(16) bf16 vt[64 * 64];
  int sblk = blockIdx.x, bh = blockIdx.y;
  int b = bh >> 4, h = bh & 15;
  int tid = threadIdx.x;
  int r = tid >> 2, c = tid & 3;
  int s = sblk * 64 + r;
  size_t rowbase = ((size_t)(b * S_LEN + s)) * 3072 + h * 192;

  bf16x8 qlo = *(const bf16x8*)(QKV + rowbase + c * 8);
  bf16x8 qhi = *(const bf16x8*)(QKV + rowbase + c * 8 + 32);
  bf16x8 klo = *(const bf16x8*)(QKV + rowbase + 64 + c * 8);
  bf16x8 khi = *(const bf16x8*)(QKV + rowbase + 64 + c * 8 + 32);
  bf16x8 vlo = *(const bf16x8*)(QKV + rowbase + 128 + c * 8);
  bf16x8 vhi = *(const bf16x8*)(QKV + rowbase + 128 + c * 8 + 32);

  bf16x8 qol, qoh, kol, koh;
#pragma unroll
  for (int j = 0; j < 8; j++) {
    float cs = ct[s * 32 + c * 8 + j], sn = st[s * 32 + c * 8 + j];
    float q1 = (float)qlo[j], q2 = (float)qhi[j];
    qol[j] = (bf16)(q1 * cs - q2 * sn);
    qoh[j] = (bf16)(q2 * cs + q1 * sn);
    float k1 = (float)klo[j], k2 = (float)khi[j];
    kol[j] = (bf16)(k1 * cs - k2 * sn);
    koh[j] = (bf16)(k2 * cs + k1 * sn);
  }
  size_t qb = ((size_t)bh * S_LEN + s) * 64 + c * 8;
  *(bf16x8*)(Q + qb) = qol;
  *(bf16x8*)(Q + qb + 32) = qoh;
  *(bf16x8*)(Kb + qb) = kol;
  *(bf16x8*)(Kb + qb + 32) = koh;

#pragma unroll
  for (int j = 0; j < 8; j++) {
    vt[(c * 8 + j) * 64 + r] = vlo[j];
    vt[(c * 8 + 32 + j) * 64 + r] = vhi[j];
  }
  __syncthreads();
  int d = tid >> 2, cc = tid & 3;
  size_t vb = ((size_t)bh * 64 + d) * S_LEN + sblk * 64 + cc * 16;
  *(bf16x8*)(Vt + vb) = *(const bf16x8*)(vt + d * 64 + cc * 16);
  *(bf16x8*)(Vt + vb + 8) = *(const bf16x8*)(vt + d * 64 + cc * 16 + 8);
}

// ---------------- Flash attention ----------------
// Block: 128 q-rows, 4 waves x 32 rows. K-tiles of 128. Online softmax.
__global__ __launch_bounds__(256, 2) void k_attn(
    const bf16* __restrict__ Q, const bf16* __restrict__ Kb,
    const bf16* __restrict__ Vt, const int* __restrict__ mask,
    bf16* __restrict__ Ctx) {
  __shared__ __align__(16) bf16 sK[128 * 64];   // [kpos][d], swz ^(row&7) on col16
  __shared__ __align__(16) bf16 sV[64 * 128];   // [d][kpos], swz ^(row&7)
  __shared__ __align__(16) bf16 sP[4 * 32 * 128];
  int tid = threadIdx.x, lane = tid & 63, wid = tid >> 6;
  int qt = blockIdx.x, bh = blockIdx.y;
  int b = bh >> 4, h = bh & 15;
  int q0 = qt * 128;

  // Q fragments, scale 1/8 (exact in bf16)
  bf16x8 aQ[2][2];
#pragma unroll
  for (int mf = 0; mf < 2; mf++)
#pragma unroll
    for (int ks = 0; ks < 2; ks++) {
      const bf16* p = Q + ((size_t)bh * S_LEN + q0 + wid * 32 + mf * 16 + (lane & 15)) * 64 +
                      ks * 32 + (lane >> 4) * 8;
      bf16x8 v = *(const bf16x8*)p;
#pragma unroll
      for (int j = 0; j < 8; j++) v[j] = (bf16)((float)v[j] * 0.125f);
      aQ[mf][ks] = v;
    }

  f32x4 O[2][4];
  float mrow[2][4], lrow[2][4];
#pragma unroll
  for (int mf = 0; mf < 2; mf++)
#pragma unroll
    for (int nd = 0; nd < 4; nd++) O[mf][nd] = (f32x4){0.f, 0.f, 0.f, 0.f};
#pragma unroll
  for (int mf = 0; mf < 2; mf++)
#pragma unroll
    for (int r = 0; r < 4; r++) { mrow[mf][r] = -3e38f; lrow[mf][r] = 0.f; }

  for (int kt = 0; kt < 16; kt++) {
    int k0 = kt * 128;
#pragma unroll
    for (int p = 0; p < 4; p++) {       // K tile: 1024 slots of 16B
      int slot = p * 256 + tid;
      int row = slot >> 3, c16 = slot & 7;
      int cs = c16 ^ (row & 7);
      gload_lds16(Kb + ((size_t)bh * S_LEN + k0 + row) * 64 + cs * 8,
                  (char*)sK + (p * 256 + wid * 64) * 16);
    }
#pragma unroll
    for (int p = 0; p < 4; p++) {       // V tile
      int slot = p * 256 + tid;
      int row = slot >> 4, c16 = slot & 15;
      int cs = c16 ^ (row & 7);
      gload_lds16(Vt + ((size_t)bh * 64 + row) * S_LEN + k0 + cs * 8,
                  (char*)sV + (p * 256 + wid * 64) * 16);
    }
    __syncthreads();

    // S = Q K^T
    f32x4 sfr[2][8];
#pragma unroll
    for (int mf = 0; mf < 2; mf++)
#pragma unroll
      for (int nf = 0; nf < 8; nf++) sfr[mf][nf] = (f32x4){0.f, 0.f, 0.f, 0.f};
#pragma unroll
    for (int nf = 0; nf < 8; nf++) {
#pragma unroll
      for (int ks = 0; ks < 2; ks++) {
        int row = nf * 16 + (lane & 15);
        int c16 = (ks * 4 + (lane >> 4)) ^ (row & 7);
        bf16x8 bk = *(const bf16x8*)((const char*)sK + row * 128 + c16 * 16);
        sfr[0][nf] = mfma16(aQ[0][ks], bk, sfr[0][nf]);
        sfr[1][nf] = mfma16(aQ[1][ks], bk, sfr[1][nf]);
      }
    }
    // mask (key positions)
#pragma unroll
    for (int nf = 0; nf < 8; nf++) {
      int kpos = k0 + nf * 16 + (lane & 15);
      if (mask[b * S_LEN + kpos] == 0) {
#pragma unroll
        for (int r = 0; r < 4; r++) { sfr[0][nf][r] = -1e30f; sfr[1][nf][r] = -1e30f; }
      }
    }
    // online softmax
    float alpha[2][4];
#pragma unroll
    for (int mf = 0; mf < 2; mf++)
#pragma unroll
      for (int r = 0; r < 4; r++) {
        float mx = -3e38f;
#pragma unroll
        for (int nf = 0; nf < 8; nf++) mx = fmaxf(mx, sfr[mf][nf][r]);
#pragma unroll
        for (int off = 1; off < 16; off <<= 1) mx = fmaxf(mx, __shfl_xor(mx, off, 64));
        float mnew = fmaxf(mrow[mf][r], mx);
        float a = __expf(mrow[mf][r] - mnew);
        mrow[mf][r] = mnew;
        float psum = 0.f;
#pragma unroll
        for (int nf = 0; nf < 8; nf++) {
          float p0 = __expf(sfr[mf][nf][r] - mnew);
          sfr[mf][nf][r] = p0;
          psum += p0;
        }
#pragma unroll
        for (int off = 1; off < 16; off <<= 1) psum += __shfl_xor(psum, off, 64);
        lrow[mf][r] = lrow[mf][r] * a + psum;
        alpha[mf][r] = a;
      }
#pragma unroll
    for (int mf = 0; mf < 2; mf++)
#pragma unroll
      for (int nd = 0; nd < 4; nd++)
#pragma unroll
        for (int r = 0; r < 4; r++) O[mf][nd][r] *= alpha[mf][r];

    // P -> wave-private LDS (bf16, swizzled), then PV
    char* pw = (char*)sP + wid * 32 * 256;
#pragma unroll
    for (int mf = 0; mf < 2; mf++)
#pragma unroll
      for (int r = 0; r < 4; r++) {
        int row = mf * 16 + (lane >> 4) * 4 + r;
#pragma unroll
        for (int nf = 0; nf < 8; nf++) {
          int col = nf * 16 + (lane & 15);
          int c16 = (col >> 3) ^ (row & 7);
          *(bf16*)(pw + row * 256 + c16 * 16 + (col & 7) * 2) = (bf16)sfr[mf][nf][r];
        }
      }
#pragma unroll
    for (int ks = 0; ks < 4; ks++) {
      bf16x8 aP[2];
#pragma unroll
      for (int mf = 0; mf < 2; mf++) {
        int row = mf * 16 + (lane & 15);
        int c16 = (ks * 4 + (lane >> 4)) ^ (row & 7);
        aP[mf] = *(const bf16x8*)(pw + row * 256 + c16 * 16);
      }
#pragma unroll
      for (int nd = 0; nd < 4; nd++) {
        int row = nd * 16 + (lane & 15);
        int c16 = (ks * 4 + (lane >> 4)) ^ (row & 7);
        bf16x8 bv = *(const bf16x8*)((const char*)sV + row * 256 + c16 * 16);
#pragma unroll
        for (int mf = 0; mf < 2; mf++) O[mf][nd] = mfma16(aP[mf], bv, O[mf][nd]);
      }
    }
    __syncthreads();
  }

#pragma unroll
  for (int mf = 0; mf < 2; mf++)
#pragma unroll
    for (int r = 0; r < 4; r++) {
      float inv = 1.f / lrow[mf][r];
      int srow = q0 + wid * 32 + mf * 16 + (lane >> 4) * 4 + r;
#pragma unroll
      for (int nd = 0; nd < 4; nd++) {
        int d = nd * 16 + (lane & 15);
        Ctx[((size_t)b * S_LEN + srow) * 1024 + h * 64 + d] = (bf16)(O[mf][nd][r] * inv);
      }
    }
}

// ---------------- out GEMM: (4096,1024)bf16 @ WoutT -> fp32 ----------------
__global__ __launch_bounds__(256, 2) void k_gemm_out(
    const bf16* __restrict__ A, const bf16* __restrict__ Bt,
    float* __restrict__ C) {
  const int K = 1024, N = 1024;
  __shared__ __align__(16) bf16 sA[128 * 32];
  __shared__ __align__(16) bf16 sB[128 * 32];
  int tid = threadIdx.x, lane = tid & 63, wid = tid >> 6;
  int m0 = blockIdx.x * 128, n0 = blockIdx.y * 128;
  int wm = wid >> 1, wn = wid & 1;

  f32x4 acc[4][4];
#pragma unroll
  for (int a = 0; a < 4; a++)
#pragma unroll
    for (int b = 0; b < 4; b++) acc[a][b] = (f32x4){0.f, 0.f, 0.f, 0.f};

  for (int k0 = 0; k0 < K; k0 += 32) {
#pragma unroll
    for (int p = 0; p < 2; p++) {
      int slot = p * 256 + tid;
      int row = slot >> 2, c16 = slot & 3;
      int cs = c16 ^ ((row >> 1) & 3);
      int ldsoff = (p * 256 + wid * 64) * 16;
      gload_lds16(A + (size_t)(m0 + row) * K + k0 + cs * 8, (char*)sA + ldsoff);
      gload_lds16(Bt + (size_t)(n0 + row) * K + k0 + cs * 8, (char*)sB + ldsoff);
    }
    __syncthreads();
    bf16x8 fa[4], fb[4];
#pragma unroll
    for (int mf = 0; mf < 4; mf++) {
      int row = wm * 64 + mf * 16 + (lane & 15);
      int c16 = (lane >> 4) ^ ((row >> 1) & 3);
      fa[mf] = *(const bf16x8*)((const char*)sA + row * 64 + c16 * 16);
    }
#pragma unroll
    for (int nf = 0; nf < 4; nf++) {
      int row = wn * 64 + nf * 16 + (lane & 15);
      int c16 = (lane >> 4) ^ ((row >> 1) & 3);
      fb[nf] = *(const bf16x8*)((const char*)sB + row * 64 + c16 * 16);
    }
#pragma unroll
    for (int mf = 0; mf < 4; mf++)
#pragma unroll
      for (int nf = 0; nf < 4; nf++)
        acc[mf][nf] = mfma16(fa[mf], fb[nf], acc[mf][nf]);
    __syncthreads();
  }
#pragma unroll
  for (int mf = 0; mf < 4; mf++)
#pragma unroll
    for (int nf = 0; nf < 4; nf++)
#pragma unroll
      for (int r = 0; r < 4; r++) {
        int row = m0 + wm * 64 + mf * 16 + (lane >> 4) * 4 + r;
        int col = n0 + wn * 64 + nf * 16 + (lane & 15);
        C[(size_t)row * N + col] = acc[mf][nf][r];
      }
}

// ---------------- launch ----------------
extern "C" void kernel_launch(void* const* d_in, const int* in_sizes, int n_in,
                              void* d_out, int out_size, void* d_ws, size_t ws_size,
                              hipStream_t stream) {
  const float* x = (const float*)d_in[0];
  const int* mask = (const int*)d_in[1];
  const float* wqkv = (const float*)d_in[2];
  const float* wout = (const float*)d_in[3];
  float* out = (float*)d_out;
  char* ws = (char*)d_ws;

  bf16* Xh  = (bf16*)(ws + 0);          // 8 MB
  bf16* Xl  = (bf16*)(ws + 8388608);    // 8 MB
  bf16* Wqh = (bf16*)(ws + 16777216);   // 6 MB
  bf16* Wql = (bf16*)(ws + 23068672);   // 6 MB
  bf16* Wo  = (bf16*)(ws + 29360128);   // 2 MB
  bf16* QKV = (bf16*)(ws + 31457280);   // 24 MB
  bf16* Qb  = (bf16*)(ws + 56623104);   // 8 MB
  bf16* Kb  = (bf16*)(ws + 65011712);   // 8 MB
  bf16* Vt  = (bf16*)(ws + 73400320);   // 8 MB
  bf16* Ctx = (bf16*)(ws + 81788928);   // 8 MB
  float* ct = (float*)(ws + 90177536);  // 256 KB
  float* st = (float*)(ws + 90439680);  // 256 KB

  k_split_x<<<4096, 256, 0, stream>>>(x, Xh, Xl);
  k_wt_qkv<<<dim3(96, 32), 256, 0, stream>>>(wqkv, Wqh, Wql);
  k_wt_out<<<dim3(32, 32), 256, 0, stream>>>(wout, Wo);
  k_rope_tables<<<256, 256, 0, stream>>>(ct, st);
  k_gemm_qkv<<<dim3(32, 24), 256, 0, stream>>>(Xh, Xl, Wqh, Wql, QKV);
  k_rope_scatter<<<dim3(32, 32), 256, 0, stream>>>(QKV, ct, st, Qb, Kb, Vt);
  k_attn<<<dim3(16, 32), 256, 0, stream>>>(Qb, Kb, Vt, mask, Ctx);
  k_gemm_out<<<dim3(32, 8), 256, 0, stream>>>(Ctx, Wo, out);
}

// Round 2
// 265.268 us; speedup vs baseline: 1.0777x; 1.0777x over previous
//
#include <hip/hip_runtime.h>
#include <hip/hip_bf16.h>
#include <math.h>
#include <stdint.h>

// MHA pipeline: split_x + transpose weights (hi/lo bf16) + rope tables ->
// split QKV GEMM (3-term bf16 MFMA = fp32-ish precision) -> rope+scatter ->
// flash attention (swapped-operand, in-register P) -> out GEMM.

typedef __bf16 bf16;
typedef __bf16 bf16x8 __attribute__((ext_vector_type(8)));
typedef __bf16 bf16x4 __attribute__((ext_vector_type(4)));
typedef float f32x4 __attribute__((ext_vector_type(4)));

#define AS1 __attribute__((address_space(1)))
#define AS3 __attribute__((address_space(3)))

__device__ __forceinline__ void gload_lds16(const void* g, void* l) {
  __builtin_amdgcn_global_load_lds((const AS1 void*)g, (AS3 void*)l, 16, 0, 0);
}

__device__ __forceinline__ f32x4 mfma16(bf16x8 a, bf16x8 b, f32x4 c) {
  return __builtin_amdgcn_mfma_f32_16x16x32_bf16(a, b, c, 0, 0, 0);
}

#define S_LEN 2048

// ---------------- prep kernels ----------------

__global__ void k_split_x(const float* __restrict__ x, bf16* __restrict__ xh,
                          bf16* __restrict__ xl) {
  int i = blockIdx.x * 256 + threadIdx.x;
  float4 v = ((const float4*)x)[i];
  float vv[4] = {v.x, v.y, v.z, v.w};
  bf16x4 h, l;
#pragma unroll
  for (int j = 0; j < 4; j++) {
    bf16 hb = (bf16)vv[j];
    h[j] = hb;
    l[j] = (bf16)(vv[j] - (float)hb);
  }
  ((bf16x4*)xh)[i] = h;
  ((bf16x4*)xl)[i] = l;
}

__global__ void k_wt_qkv(const float* __restrict__ w, bf16* __restrict__ bth,
                         bf16* __restrict__ btl) {
  __shared__ float t[32][33];
  int n0 = blockIdx.x * 32, k0 = blockIdx.y * 32;
  int tx = threadIdx.x & 31, ty = threadIdx.x >> 5;
#pragma unroll
  for (int i = 0; i < 4; i++)
    t[ty + 8 * i][tx] = w[(size_t)(k0 + ty + 8 * i) * 3072 + n0 + tx];
  __syncthreads();
#pragma unroll
  for (int i = 0; i < 4; i++) {
    int r = ty + 8 * i;
    float v = t[tx][r];
    size_t o = (size_t)(n0 + r) * 1024 + k0 + tx;
    bf16 hb = (bf16)v;
    bth[o] = hb;
    btl[o] = (bf16)(v - (float)hb);
  }
}

__global__ void k_wt_out(const float* __restrict__ w, bf16* __restrict__ bt) {
  __shared__ float t[32][33];
  int n0 = blockIdx.x * 32, k0 = blockIdx.y * 32;
  int tx = threadIdx.x & 31, ty = threadIdx.x >> 5;
#pragma unroll
  for (int i = 0; i < 4; i++)
    t[ty + 8 * i][tx] = w[(size_t)(k0 + ty + 8 * i) * 1024 + n0 + tx];
  __syncthreads();
#pragma unroll
  for (int i = 0; i < 4; i++) {
    int r = ty + 8 * i;
    bt[(size_t)(n0 + r) * 1024 + k0 + tx] = (bf16)t[tx][r];
  }
}

__global__ void k_rope_tables(float* __restrict__ ct, float* __restrict__ st) {
  int i = blockIdx.x * 256 + threadIdx.x;   // 65536
  int s = i >> 5, j = i & 31;
  double invf = pow(10000.0, -(double)j / 32.0);
  double a = (double)s * invf;
  ct[i] = (float)cos(a);
  st[i] = (float)sin(a);
}

// ---------------- QKV GEMM ----------------
__global__ __launch_bounds__(256, 2) void k_gemm_qkv(
    const bf16* __restrict__ Ah, const bf16* __restrict__ Al,
    const bf16* __restrict__ Bh, const bf16* __restrict__ Bl,
    bf16* __restrict__ C) {
  const int K = 1024, N = 3072;
  __shared__ __align__(16) bf16 sAh[128 * 32];
  __shared__ __align__(16) bf16 sAl[128 * 32];
  __shared__ __align__(16) bf16 sBh[128 * 32];
  __shared__ __align__(16) bf16 sBl[128 * 32];
  int tid = threadIdx.x, lane = tid & 63, wid = tid >> 6;
  int m0 = blockIdx.x * 128, n0 = blockIdx.y * 128;
  int wm = wid >> 1, wn = wid & 1;

  f32x4 acc[4][4];
#pragma unroll
  for (int a = 0; a < 4; a++)
#pragma unroll
    for (int b = 0; b < 4; b++) acc[a][b] = (f32x4){0.f, 0.f, 0.f, 0.f};

  for (int k0 = 0; k0 < K; k0 += 32) {
#pragma unroll
    for (int p = 0; p < 2; p++) {
      int slot = p * 256 + tid;
      int row = slot >> 2, c16 = slot & 3;
      int cs = c16 ^ ((row >> 1) & 3);
      int ldsoff = (p * 256 + wid * 64) * 16;
      size_t ga = (size_t)(m0 + row) * K + k0 + cs * 8;
      size_t gb = (size_t)(n0 + row) * K + k0 + cs * 8;
      gload_lds16(Ah + ga, (char*)sAh + ldsoff);
      gload_lds16(Al + ga, (char*)sAl + ldsoff);
      gload_lds16(Bh + gb, (char*)sBh + ldsoff);
      gload_lds16(Bl + gb, (char*)sBl + ldsoff);
    }
    __syncthreads();

    bf16x8 fah[4], fal[4], fbh[4], fbl[4];
#pragma unroll
    for (int mf = 0; mf < 4; mf++) {
      int row = wm * 64 + mf * 16 + (lane & 15);
      int c16 = (lane >> 4) ^ ((row >> 1) & 3);
      int off = row * 64 + c16 * 16;
      fah[mf] = *(const bf16x8*)((const char*)sAh + off);
      fal[mf] = *(const bf16x8*)((const char*)sAl + off);
    }
#pragma unroll
    for (int nf = 0; nf < 4; nf++) {
      int row = wn * 64 + nf * 16 + (lane & 15);
      int c16 = (lane >> 4) ^ ((row >> 1) & 3);
      int off = row * 64 + c16 * 16;
      fbh[nf] = *(const bf16x8*)((const char*)sBh + off);
      fbl[nf] = *(const bf16x8*)((const char*)sBl + off);
    }
#pragma unroll
    for (int mf = 0; mf < 4; mf++)
#pragma unroll
      for (int nf = 0; nf < 4; nf++) {
        acc[mf][nf] = mfma16(fah[mf], fbh[nf], acc[mf][nf]);
        acc[mf][nf] = mfma16(fah[mf], fbl[nf], acc[mf][nf]);
        acc[mf][nf] = mfma16(fal[mf], fbh[nf], acc[mf][nf]);
      }
    __syncthreads();
  }

#pragma unroll
  for (int mf = 0; mf < 4; mf++)
#pragma unroll
    for (int nf = 0; nf < 4; nf++)
#pragma unroll
      for (int r = 0; r < 4; r++) {
        int row = m0 + wm * 64 + mf * 16 + (lane >> 4) * 4 + r;
        int col = n0 + wn * 64 + nf * 16 + (lane & 15);
        C[(size_t)row * N + col] = (bf16)acc[mf][nf][r];
      }
}

// ---------------- RoPE + scatter ----------------
__global__ void k_rope_scatter(const bf16* __restrict__ QKV,
                               const float* __restrict__ ct,
                               const float* __restrict__ st,
                               bf16* __restrict__ Q, bf16* __restrict__ Kb,
                               bf16* __restrict__ Vt) {
  __shared__ __align__(16) bf16 vt[64 * 64];
  int sblk = blockIdx.x, bh = blockIdx.y;
  int b = bh >> 4, h = bh & 15;
  int tid = threadIdx.x;
  int r = tid >> 2, c = tid & 3;
  int s = sblk * 64 + r;
  size_t rowbase = ((size_t)(b * S_LEN + s)) * 3072 + h * 192;

  bf16x8 qlo = *(const bf16x8*)(QKV + rowbase + c * 8);
  bf16x8 qhi = *(const bf16x8*)(QKV + rowbase + c * 8 + 32);
  bf16x8 klo = *(const bf16x8*)(QKV + rowbase + 64 + c * 8);
  bf16x8 khi = *(const bf16x8*)(QKV + rowbase + 64 + c * 8 + 32);
  bf16x8 vlo = *(const bf16x8*)(QKV + rowbase + 128 + c * 8);
  bf16x8 vhi = *(const bf16x8*)(QKV + rowbase + 128 + c * 8 + 32);

  bf16x8 qol, qoh, kol, koh;
#pragma unroll
  for (int j = 0; j < 8; j++) {
    float cs = ct[s * 32 + c * 8 + j], sn = st[s * 32 + c * 8 + j];
    float q1 = (float)qlo[j], q2 = (float)qhi[j];
    qol[j] = (bf16)(q1 * cs - q2 * sn);
    qoh[j] = (bf16)(q2 * cs + q1 * sn);
    float k1 = (float)klo[j], k2 = (float)khi[j];
    kol[j] = (bf16)(k1 * cs - k2 * sn);
    koh[j] = (bf16)(k2 * cs + k1 * sn);
  }
  size_t qb = ((size_t)bh * S_LEN + s) * 64 + c * 8;
  *(bf16x8*)(Q + qb) = qol;
  *(bf16x8*)(Q + qb + 32) = qoh;
  *(bf16x8*)(Kb + qb) = kol;
  *(bf16x8*)(Kb + qb + 32) = koh;

#pragma unroll
  for (int j = 0; j < 8; j++) {
    vt[(c * 8 + j) * 64 + r] = vlo[j];
    vt[(c * 8 + 32 + j) * 64 + r] = vhi[j];
  }
  __syncthreads();
  int d = tid >> 2, cc = tid & 3;
  size_t vb = ((size_t)bh * 64 + d) * S_LEN + sblk * 64 + cc * 16;
  *(bf16x8*)(Vt + vb) = *(const bf16x8*)(vt + d * 64 + cc * 16);
  *(bf16x8*)(Vt + vb + 8) = *(const bf16x8*)(vt + d * 64 + cc * 16 + 8);
}

// ---------------- Flash attention (swapped operands, in-register P) ----------
// S^T = mfma(K, Q): lane holds S^T[key = kf*16+g*4+r][q = lane&15 (+16*mf)]
// -> softmax lane-local (2 shfl_xor per reduce).
// O^T = mfma(V^T, P^T) with permuted k-slot mapping pi(ks,g,j) =
// ks*32 + (j>>2)*16 + g*4 + (j&3) applied to BOTH operands (exact: MFMA sums
// over k-slots, any consistent permutation is identity on the result).
// P^T B-frag then comes from the lane's own sfr registers: zero cross-lane.
__global__ __launch_bounds__(256, 3) void k_attn(
    const bf16* __restrict__ Q, const bf16* __restrict__ Kb,
    const bf16* __restrict__ Vt, const int* __restrict__ mask,
    bf16* __restrict__ Ctx) {
  __shared__ __align__(16) bf16 sK[128 * 64];   // [key][d], c16 ^= (key&7)
  __shared__ __align__(16) bf16 sV[64 * 128];   // [d][key], c16 ^= (d&7)
  int tid = threadIdx.x, lane = tid & 63, wid = tid >> 6;
  int g = lane >> 4, q = lane & 15;
  int qt = blockIdx.x, bh = blockIdx.y;
  int b = bh >> 4, h = bh & 15;
  int q0 = qt * 128 + wid * 32;

  // Q as B-operand: col = q, k-elems d = g*8+j. Scale 1/8 (exact in bf16).
  bf16x8 bQ[2][2];
#pragma unroll
  for (int mf = 0; mf < 2; mf++)
#pragma unroll
    for (int ks = 0; ks < 2; ks++) {
      const bf16* p = Q + ((size_t)bh * S_LEN + q0 + mf * 16 + q) * 64 + ks * 32 + g * 8;
      bf16x8 v = *(const bf16x8*)p;
#pragma unroll
      for (int j = 0; j < 8; j++) v[j] = (bf16)((float)v[j] * 0.125f);
      bQ[mf][ks] = v;
    }

  f32x4 O[2][4];            // O^T: [q-block mf][d-block nd], row=d, col=q
  float mrow[2], lrow[2];
#pragma unroll
  for (int mf = 0; mf < 2; mf++) {
#pragma unroll
    for (int nd = 0; nd < 4; nd++) O[mf][nd] = (f32x4){0.f, 0.f, 0.f, 0.f};
    mrow[mf] = -3e38f;
    lrow[mf] = 0.f;
  }

  for (int kt = 0; kt < 16; kt++) {
    int k0 = kt * 128;
#pragma unroll
    for (int p = 0; p < 4; p++) {       // K tile
      int slot = p * 256 + tid;
      int row = slot >> 3, c16 = slot & 7;
      int cs = c16 ^ (row & 7);
      gload_lds16(Kb + ((size_t)bh * S_LEN + k0 + row) * 64 + cs * 8,
                  (char*)sK + (p * 256 + wid * 64) * 16);
    }
#pragma unroll
    for (int p = 0; p < 4; p++) {       // V tile
      int slot = p * 256 + tid;
      int row = slot >> 4, c16 = slot & 15;
      int cs = c16 ^ (row & 7);
      gload_lds16(Vt + ((size_t)bh * 64 + row) * S_LEN + k0 + cs * 8,
                  (char*)sV + (p * 256 + wid * 64) * 16);
    }
    __syncthreads();

    // S^T = K Q^T
    f32x4 sfr[2][8];
#pragma unroll
    for (int mf = 0; mf < 2; mf++)
#pragma unroll
      for (int kf = 0; kf < 8; kf++) sfr[mf][kf] = (f32x4){0.f, 0.f, 0.f, 0.f};
#pragma unroll
    for (int kf = 0; kf < 8; kf++) {
#pragma unroll
      for (int ks = 0; ks < 2; ks++) {
        int row = kf * 16 + q;                      // key row
        int c16 = (ks * 4 + g) ^ (row & 7);
        bf16x8 ak = *(const bf16x8*)((const char*)sK + row * 128 + c16 * 16);
        sfr[0][kf] = mfma16(ak, bQ[0][ks], sfr[0][kf]);
        sfr[1][kf] = mfma16(ak, bQ[1][ks], sfr[1][kf]);
      }
    }
    // mask over key positions (lane's keys: kf*16 + g*4 + r)
#pragma unroll
    for (int kf = 0; kf < 8; kf++) {
      int4 mv = *(const int4*)(mask + b * S_LEN + k0 + kf * 16 + g * 4);
      int mm[4] = {mv.x, mv.y, mv.z, mv.w};
#pragma unroll
      for (int r = 0; r < 4; r++)
        if (mm[r] == 0) { sfr[0][kf][r] = -1e30f; sfr[1][kf][r] = -1e30f; }
    }
    // online softmax: lane-local over 32 values + 2 shfl_xor
    float alpha[2];
#pragma unroll
    for (int mf = 0; mf < 2; mf++) {
      float mx = -3e38f;
#pragma unroll
      for (int kf = 0; kf < 8; kf++)
#pragma unroll
        for (int r = 0; r < 4; r++) mx = fmaxf(mx, sfr[mf][kf][r]);
      mx = fmaxf(mx, __shfl_xor(mx, 16, 64));
      mx = fmaxf(mx, __shfl_xor(mx, 32, 64));
      float mnew = fmaxf(mrow[mf], mx);
      float al = __expf(mrow[mf] - mnew);
      mrow[mf] = mnew;
      float ps = 0.f;
#pragma unroll
      for (int kf = 0; kf < 8; kf++)
#pragma unroll
        for (int r = 0; r < 4; r++) {
          float p0 = __expf(sfr[mf][kf][r] - mnew);
          sfr[mf][kf][r] = p0;
          ps += p0;
        }
      ps += __shfl_xor(ps, 16, 64);
      ps += __shfl_xor(ps, 32, 64);
      lrow[mf] = lrow[mf] * al + ps;
      alpha[mf] = al;
    }
#pragma unroll
    for (int mf = 0; mf < 2; mf++)
#pragma unroll
      for (int nd = 0; nd < 4; nd++)
#pragma unroll
        for (int r = 0; r < 4; r++) O[mf][nd][r] *= alpha[mf];

    // PV with permuted k-slots; P^T fragment from own registers
#pragma unroll
    for (int ks = 0; ks < 4; ks++) {
      bf16x8 pb[2];
#pragma unroll
      for (int mf = 0; mf < 2; mf++)
#pragma unroll
        for (int j = 0; j < 8; j++)
          pb[mf][j] = (bf16)sfr[mf][2 * ks + (j >> 2)][j & 3];
#pragma unroll
      for (int nd = 0; nd < 4; nd++) {
        int row = nd * 16 + q;                      // d row
        int sw = (row & 7) << 4;
        bf16x4 v0 = *(const bf16x4*)((const char*)sV + row * 256 + ((ks * 64 + g * 8) ^ sw));
        bf16x4 v1 = *(const bf16x4*)((const char*)sV + row * 256 + ((ks * 64 + g * 8 + 32) ^ sw));
        bf16x8 av;
#pragma unroll
        for (int j = 0; j < 4; j++) { av[j] = v0[j]; av[4 + j] = v1[j]; }
#pragma unroll
        for (int mf = 0; mf < 2; mf++) O[mf][nd] = mfma16(av, pb[mf], O[mf][nd]);
      }
    }
    __syncthreads();
  }

#pragma unroll
  for (int mf = 0; mf < 2; mf++) {
    float inv = 1.f / lrow[mf];
    int srow = q0 + mf * 16 + q;
#pragma unroll
    for (int nd = 0; nd < 4; nd++) {
      bf16x4 o4;
#pragma unroll
      for (int r = 0; r < 4; r++) o4[r] = (bf16)(O[mf][nd][r] * inv);
      *(bf16x4*)(Ctx + ((size_t)b * S_LEN + srow) * 1024 + h * 64 + nd * 16 + g * 4) = o4;
    }
  }
}

// ---------------- out GEMM ----------------
__global__ __launch_bounds__(256, 2) void k_gemm_out(
    const bf16* __restrict__ A, const bf16* __restrict__ Bt,
    float* __restrict__ C) {
  const int K = 1024, N = 1024;
  __shared__ __align__(16) bf16 sA[128 * 32];
  __shared__ __align__(16) bf16 sB[128 * 32];
  int tid = threadIdx.x, lane = tid & 63, wid = tid >> 6;
  int m0 = blockIdx.x * 128, n0 = blockIdx.y * 128;
  int wm = wid >> 1, wn = wid & 1;

  f32x4 acc[4][4];
#pragma unroll
  for (int a = 0; a < 4; a++)
#pragma unroll
    for (int b = 0; b < 4; b++) acc[a][b] = (f32x4){0.f, 0.f, 0.f, 0.f};

  for (int k0 = 0; k0 < K; k0 += 32) {
#pragma unroll
    for (int p = 0; p < 2; p++) {
      int slot = p * 256 + tid;
      int row = slot >> 2, c16 = slot & 3;
      int cs = c16 ^ ((row >> 1) & 3);
      int ldsoff = (p * 256 + wid * 64) * 16;
      gload_lds16(A + (size_t)(m0 + row) * K + k0 + cs * 8, (char*)sA + ldsoff);
      gload_lds16(Bt + (size_t)(n0 + row) * K + k0 + cs * 8, (char*)sB + ldsoff);
    }
    __syncthreads();
    bf16x8 fa[4], fb[4];
#pragma unroll
    for (int mf = 0; mf < 4; mf++) {
      int row = wm * 64 + mf * 16 + (lane & 15);
      int c16 = (lane >> 4) ^ ((row >> 1) & 3);
      fa[mf] = *(const bf16x8*)((const char*)sA + row * 64 + c16 * 16);
    }
#pragma unroll
    for (int nf = 0; nf < 4; nf++) {
      int row = wn * 64 + nf * 16 + (lane & 15);
      int c16 = (lane >> 4) ^ ((row >> 1) & 3);
      fb[nf] = *(const bf16x8*)((const char*)sB + row * 64 + c16 * 16);
    }
#pragma unroll
    for (int mf = 0; mf < 4; mf++)
#pragma unroll
      for (int nf = 0; nf < 4; nf++)
        acc[mf][nf] = mfma16(fa[mf], fb[nf], acc[mf][nf]);
    __syncthreads();
  }
#pragma unroll
  for (int mf = 0; mf < 4; mf++)
#pragma unroll
    for (int nf = 0; nf < 4; nf++)
#pragma unroll
      for (int r = 0; r < 4; r++) {
        int row = m0 + wm * 64 + mf * 16 + (lane >> 4) * 4 + r;
        int col = n0 + wn * 64 + nf * 16 + (lane & 15);
        C[(size_t)row * N + col] = acc[mf][nf][r];
      }
}

// ---------------- launch ----------------
extern "C" void kernel_launch(void* const* d_in, const int* in_sizes, int n_in,
                              void* d_out, int out_size, void* d_ws, size_t ws_size,
                              hipStream_t stream) {
  const float* x = (const float*)d_in[0];
  const int* mask = (const int*)d_in[1];
  const float* wqkv = (const float*)d_in[2];
  const float* wout = (const float*)d_in[3];
  float* out = (float*)d_out;
  char* ws = (char*)d_ws;

  bf16* Xh  = (bf16*)(ws + 0);
  bf16* Xl  = (bf16*)(ws + 8388608);
  bf16* Wqh = (bf16*)(ws + 16777216);
  bf16* Wql = (bf16*)(ws + 23068672);
  bf16* Wo  = (bf16*)(ws + 29360128);
  bf16* QKV = (bf16*)(ws + 31457280);
  bf16* Qb  = (bf16*)(ws + 56623104);
  bf16* Kb  = (bf16*)(ws + 65011712);
  bf16* Vt  = (bf16*)(ws + 73400320);
  bf16* Ctx = (bf16*)(ws + 81788928);
  float* ct = (float*)(ws + 90177536);
  float* st = (float*)(ws + 90439680);

  k_split_x<<<4096, 256, 0, stream>>>(x, Xh, Xl);
  k_wt_qkv<<<dim3(96, 32), 256, 0, stream>>>(wqkv, Wqh, Wql);
  k_wt_out<<<dim3(32, 32), 256, 0, stream>>>(wout, Wo);
  k_rope_tables<<<256, 256, 0, stream>>>(ct, st);
  k_gemm_qkv<<<dim3(32, 24), 256, 0, stream>>>(Xh, Xl, Wqh, Wql, QKV);
  k_rope_scatter<<<dim3(32, 32), 256, 0, stream>>>(QKV, ct, st, Qb, Kb, Vt);
  k_attn<<<dim3(16, 32), 256, 0, stream>>>(Qb, Kb, Vt, mask, Ctx);
  k_gemm_out<<<dim3(32, 8), 256, 0, stream>>>(Ctx, Wo, out);
}